// Round 12
// baseline (171.618 us; speedup 1.0000x reference)
//
#include <hip/hip_runtime.h>
#include <stdint.h>

#define HH 2048
#define WW 2048
#define HW (HH * WW)
#define N4 (HW / 4)
#define FB 512      // fine histogram bins over fixed [0,1)
#define G1H 256     // hist blocks (1024 thr, 4 hoisted iters: 256*1024*4 == N4)
#define G3M 512     // main blocks (1024 thr): one 2-row strip per thread (clean-WRITE shape)
#define STRIDE (G1H * 1024)

// ws uint32 layout (ONLY words [0..518] used — PROVEN-SAFE region):
// [0..511]   fine hist (u32); AFTER hist_k last block: [0..255]=cdf(float), [256]=gmin, [257]=gmax
// [320,336,352,368,384,400]  acc floats on 6 DISTINCT 64B cachelines (dead bin words, zeroed by
//            hist_k's last block after bins are copied to LDS; stream order makes this visible
//            to main_k):  0=recon_low 1=recon_eq 2=sum|dRg| 3=sumRg 4=sum|dL|e^-10|dRg|
//            5=sum L*e^-10Rg.  Chain-parallel: 512-deep per line x 7 lines (incl. counter).
// [518]      SHARED done counter (alone on its line w.r.t. atomics): hist adds G1H, main adds G3M.

#define PIN4(a, b, c, d) \
    asm volatile("" :: "v"(a), "v"(b), "v"(c), "v"(d))
#define PIN12(a, b, c, d, e, f, g, h, i, j, k, l)                             \
    asm volatile("" :: "v"(a), "v"(b), "v"(c), "v"(d), "v"(e), "v"(f),        \
                       "v"(g), "v"(h), "v"(i), "v"(j), "v"(k), "v"(l))
#define PIN14(a, b, c, d, e, f, g, h, i, j, k, l, m, n)                       \
    asm volatile("" :: "v"(a), "v"(b), "v"(c), "v"(d), "v"(e), "v"(f),        \
                       "v"(g), "v"(h), "v"(i), "v"(j), "v"(k), "v"(l),        \
                       "v"(m), "v"(n))

__device__ __forceinline__ float gray_pil(float r, float g, float b) {
    float qr = floorf(fminf(fmaxf(r, 0.f), 1.f) * 255.f);
    float qg = floorf(fminf(fmaxf(g, 0.f), 1.f) * 255.f);
    float qb = floorf(fminf(fmaxf(b, 0.f), 1.f) * 255.f);
    // all terms integers < 2^24: exact in fp32
    float s = floorf((qr * 19595.f + qg * 38470.f + qb * 7471.f + 32768.f) * (1.f / 65536.f));
    return s * (1.f / 255.f);
}

// ---------------- K1: fine histogram + (last block) cdf derivation ----------------
__global__ __launch_bounds__(1024, 1)
void hist_k(const float* __restrict__ im, uint32_t* __restrict__ ctl) {
    __shared__ uint32_t lh[FB];
    __shared__ uint32_t sc[256];
    __shared__ uint32_t smm[2];
    __shared__ uint32_t lastf;
    int t = threadIdx.x;
    if (t < FB) lh[t] = 0u;
    __syncthreads();

    const float4* im4 = (const float4*)im;
    int tid = blockIdx.x * 1024 + t;
    float4 A0 = im4[tid],              B0 = im4[tid + N4],              C0 = im4[tid + 2 * N4];
    float4 A1 = im4[tid + STRIDE],     B1 = im4[tid + STRIDE + N4],     C1 = im4[tid + STRIDE + 2 * N4];
    float4 A2 = im4[tid + 2 * STRIDE], B2 = im4[tid + 2 * STRIDE + N4], C2 = im4[tid + 2 * STRIDE + 2 * N4];
    float4 A3 = im4[tid + 3 * STRIDE], B3 = im4[tid + 3 * STRIDE + N4], C3 = im4[tid + 3 * STRIDE + 2 * N4];
    PIN12(A0.x, B0.x, C0.x, A1.x, B1.x, C1.x,
          A2.x, B2.x, C2.x, A3.x, B3.x, C3.x);

#define HBIN(a, b, c) { \
        float m0 = fmaxf(a.x, fmaxf(b.x, c.x)); \
        float m1 = fmaxf(a.y, fmaxf(b.y, c.y)); \
        float m2 = fmaxf(a.z, fmaxf(b.z, c.z)); \
        float m3 = fmaxf(a.w, fmaxf(b.w, c.w)); \
        int b0 = (int)(m0 * (float)FB); b0 = b0 < 0 ? 0 : (b0 > FB - 1 ? FB - 1 : b0); \
        int b1 = (int)(m1 * (float)FB); b1 = b1 < 0 ? 0 : (b1 > FB - 1 ? FB - 1 : b1); \
        int b2 = (int)(m2 * (float)FB); b2 = b2 < 0 ? 0 : (b2 > FB - 1 ? FB - 1 : b2); \
        int b3 = (int)(m3 * (float)FB); b3 = b3 < 0 ? 0 : (b3 > FB - 1 ? FB - 1 : b3); \
        atomicAdd(&lh[b0], 1u); atomicAdd(&lh[b1], 1u); \
        atomicAdd(&lh[b2], 1u); atomicAdd(&lh[b3], 1u); }
    HBIN(A0, B0, C0)
    HBIN(A1, B1, C1)
    HBIN(A2, B2, C2)
    HBIN(A3, B3, C3)
#undef HBIN

    __syncthreads();
    // paired 64-bit flush, rotated start per block (R5/R6-proven numerics)
    if (t < 256) {
        int pr = (t + blockIdx.x * 7) & 255;
        unsigned long long v = (unsigned long long)lh[2 * pr]
                             | ((unsigned long long)lh[2 * pr + 1] << 32);
        if (v) atomicAdd((unsigned long long*)&ctl[2 * pr], v);
    }
    __syncthreads();
    if (t == 0) {
        __threadfence();
        lastf = (atomicAdd(&ctl[518], 1u) == G1H - 1) ? 1u : 0u;
    }
    __syncthreads();
    if (!lastf) return;

    // ---- last block only: derive 256-bin cdf (exact original cdf_k numerics) ----
    if (t < FB) lh[t] = atomicAdd(&ctl[t], 0u);   // device-scope read: sees all flush atomics
    if (t < 256) sc[t] = 0u;
    if (t == 0) { smm[0] = FB; smm[1] = 0u; }
    __syncthreads();
    // bins now copied to LDS -> the 6 acc words (320+16k) are dead; zero them for main_k.
    // (kernel completion + stream order make these plain stores visible to main_k)
    if (t < 6) ctl[320 + 16 * t] = 0u;
    if (t < FB && lh[t]) { atomicMin(&smm[0], (uint32_t)t); atomicMax(&smm[1], (uint32_t)t); }
    __syncthreads();
    float gmin = (float)smm[0] * (1.0f / (float)FB);         // left edge of first nonempty fine bin
    float gmax = (float)(smm[1] + 1u) * (1.0f / (float)FB);  // right edge of last nonempty fine bin
    float inv_dw = 256.0f / (gmax - gmin);
    if (t < FB && lh[t]) {
        float c = ((float)t + 0.5f) * (1.0f / (float)FB);    // fine-bin center
        int q = (int)((c - gmin) * inv_dw);
        q = q < 0 ? 0 : (q > 255 ? 255 : q);
        atomicAdd(&sc[q], lh[t]);
    }
    __syncthreads();
    for (int d = 1; d < 256; d <<= 1) {                      // deterministic integer scan
        uint32_t v = (t < 256 && t >= d) ? sc[t - d] : 0u;
        __syncthreads();
        if (t < 256) sc[t] += v;
        __syncthreads();
    }
    float* cf = (float*)ctl;
    if (t < 256) cf[t] = (float)((double)sc[t] * (1.0 / (double)HW));
    if (t == 0) { cf[256] = gmin; cf[257] = gmax; }
}

// ---------------- K2: fused main pass + finalize ----------------
__device__ __forceinline__ void px(float r0, float r1, float r2,
                                   float i0, float i1, float i2, float l,
                                   float& rgp, float& lp,
                                   const float* __restrict__ scdf, float gmin, float inv_dw,
                                   float& a0, float& a1, float& a2,
                                   float& a3, float& a4, float& a5) {
    a0 += fabsf(r0 * l - i0) + fabsf(r1 * l - i1) + fabsf(r2 * l - i2);
    float rmax = fmaxf(r0, fmaxf(r1, r2));
    float imax = fmaxf(i0, fmaxf(i1, i2));
    float t = (imax - gmin) * inv_dw;
    t = fmaxf(t, 0.f);
    int bi = (int)t;
    float eq;
    if (bi >= 255) eq = scdf[255];
    else {
        float fr = t - (float)bi;
        eq = scdf[bi] + fr * (scdf[bi + 1] - scdf[bi]);
    }
    a1 += fabsf(rmax - eq);
    float rg = gray_pil(r0, r1, r2);
    a3 += rg;
    a5 += l * __expf(-10.f * rg);
    float drg = fabsf(rg - rgp);
    a2 += drg;
    a4 += fabsf(l - lp) * __expf(-10.f * drg);
    rgp = rg;
    lp = l;
}

// R7/R9/R11 streaming structure, finalize now ALWAYS chain-parallel (6 distinct lines).
__global__ __launch_bounds__(1024, 1)
void main_k(const float* __restrict__ im, const float* __restrict__ R,
            const float* __restrict__ L, uint32_t* __restrict__ ctl,
            float* __restrict__ out) {
    __shared__ float scdf[256];
    __shared__ float red[6][16];
    __shared__ uint32_t lastf;
    int t = threadIdx.x;

    const float* cf = (const float*)ctl;
    if (t < 256) scdf[t] = cf[t];
    float gmin = cf[256];
    float gmax = cf[257];
    float inv_dw = 256.0f / (gmax - gmin);
    __syncthreads();

    int w = (t & 511) * 4;                    // 4 adjacent columns per thread
    int h0 = blockIdx.x * 4 + ((t >> 9) * 2); // 2-row strip per thread (rows h0, h0+1)
    const int p1 = h0 * WW + w;
    const int p2 = p1 + WW;

    float4 Pa, Pb, Pc, Pl;
    if (h0 > 0) {                              // wave-uniform branch (t>>9 constant per wave)
        int pp = p1 - WW;
        Pa = *(const float4*)(R + pp);
        Pb = *(const float4*)(R + pp + HW);
        Pc = *(const float4*)(R + pp + 2 * HW);
        Pl = *(const float4*)(L + pp);
        PIN4(Pa.x, Pb.x, Pc.x, Pl.x);
    }
    float4 r0a = *(const float4*)(R + p1);
    float4 r0b = *(const float4*)(R + p1 + HW);
    float4 r0c = *(const float4*)(R + p1 + 2 * HW);
    float4 i0a = *(const float4*)(im + p1);
    float4 i0b = *(const float4*)(im + p1 + HW);
    float4 i0c = *(const float4*)(im + p1 + 2 * HW);
    float4 l0  = *(const float4*)(L + p1);
    float4 r1a = *(const float4*)(R + p2);
    float4 r1b = *(const float4*)(R + p2 + HW);
    float4 r1c = *(const float4*)(R + p2 + 2 * HW);
    float4 i1a = *(const float4*)(im + p2);
    float4 i1b = *(const float4*)(im + p2 + HW);
    float4 i1c = *(const float4*)(im + p2 + 2 * HW);
    float4 l1  = *(const float4*)(L + p2);
    PIN14(r0a.x, r0b.x, r0c.x, i0a.x, i0b.x, i0c.x, l0.x,
          r1a.x, r1b.x, r1c.x, i1a.x, i1b.x, i1c.x, l1.x);

    float a0 = 0.f, a1 = 0.f, a2 = 0.f, a3 = 0.f, a4 = 0.f, a5 = 0.f;
    float rgp[4], lp[4];
    if (h0 > 0) {
        rgp[0] = gray_pil(Pa.x, Pb.x, Pc.x); lp[0] = Pl.x;
        rgp[1] = gray_pil(Pa.y, Pb.y, Pc.y); lp[1] = Pl.y;
        rgp[2] = gray_pil(Pa.z, Pb.z, Pc.z); lp[2] = Pl.z;
        rgp[3] = gray_pil(Pa.w, Pb.w, Pc.w); lp[3] = Pl.w;
    } else {
        rgp[0] = rgp[1] = rgp[2] = rgp[3] = 0.f;
        lp[0] = lp[1] = lp[2] = lp[3] = 0.f;
    }

    // row h0
    px(r0a.x, r0b.x, r0c.x, i0a.x, i0b.x, i0c.x, l0.x, rgp[0], lp[0], scdf, gmin, inv_dw, a0, a1, a2, a3, a4, a5);
    px(r0a.y, r0b.y, r0c.y, i0a.y, i0b.y, i0c.y, l0.y, rgp[1], lp[1], scdf, gmin, inv_dw, a0, a1, a2, a3, a4, a5);
    px(r0a.z, r0b.z, r0c.z, i0a.z, i0b.z, i0c.z, l0.z, rgp[2], lp[2], scdf, gmin, inv_dw, a0, a1, a2, a3, a4, a5);
    px(r0a.w, r0b.w, r0c.w, i0a.w, i0b.w, i0c.w, l0.w, rgp[3], lp[3], scdf, gmin, inv_dw, a0, a1, a2, a3, a4, a5);
    // row h0+1
    px(r1a.x, r1b.x, r1c.x, i1a.x, i1b.x, i1c.x, l1.x, rgp[0], lp[0], scdf, gmin, inv_dw, a0, a1, a2, a3, a4, a5);
    px(r1a.y, r1b.y, r1c.y, i1a.y, i1b.y, i1c.y, l1.y, rgp[1], lp[1], scdf, gmin, inv_dw, a0, a1, a2, a3, a4, a5);
    px(r1a.z, r1b.z, r1c.z, i1a.z, i1b.z, i1c.z, l1.z, rgp[2], lp[2], scdf, gmin, inv_dw, a0, a1, a2, a3, a4, a5);
    px(r1a.w, r1b.w, r1c.w, i1a.w, i1b.w, i1c.w, l1.w, rgp[3], lp[3], scdf, gmin, inv_dw, a0, a1, a2, a3, a4, a5);

    if (h0 + 2 == HH) {  // boundary at h = 2048: |0 - x[2047]|
#pragma unroll
        for (int j = 0; j < 4; ++j) {
            a2 += rgp[j];
            a4 += lp[j] * __expf(-10.f * rgp[j]);
        }
    }

    for (int off = 32; off; off >>= 1) {
        a0 += __shfl_down(a0, off);
        a1 += __shfl_down(a1, off);
        a2 += __shfl_down(a2, off);
        a3 += __shfl_down(a3, off);
        a4 += __shfl_down(a4, off);
        a5 += __shfl_down(a5, off);
    }
    int lane = t & 63, wv = t >> 6;
    if (lane == 0) {
        red[0][wv] = a0; red[1][wv] = a1; red[2][wv] = a2;
        red[3][wv] = a3; red[4][wv] = a4; red[5][wv] = a5;
    }
    __syncthreads();
    if (t == 0) {
        float s0 = 0, s1 = 0, s2 = 0, s3 = 0, s4 = 0, s5 = 0;
        for (int k = 0; k < 16; k++) {
            s0 += red[0][k]; s1 += red[1][k]; s2 += red[2][k];
            s3 += red[3][k]; s4 += red[4][k]; s5 += red[5][k];
        }
        float* accf = (float*)ctl;
        atomicAdd(&accf[320], s0);  // 6 accs on 6 distinct 64B lines: chains drain in parallel
        atomicAdd(&accf[336], s1);
        atomicAdd(&accf[352], s2);
        atomicAdd(&accf[368], s3);
        atomicAdd(&accf[384], s4);
        atomicAdd(&accf[400], s5);
        __threadfence();
        lastf = (atomicAdd(&ctl[518], 1u) == (uint32_t)(G1H + G3M - 1)) ? 1u : 0u;
    }
    __syncthreads();
    if (!lastf) return;

    // ---- last block: final combine (atomic reads see all prior release-fenced adds) ----
    if (t == 0) {
        float* accf = (float*)ctl;
        float v0 = atomicAdd(&accf[320], 0.f);
        float v1 = atomicAdd(&accf[336], 0.f);
        float v2 = atomicAdd(&accf[352], 0.f);
        float v3 = atomicAdd(&accf[368], 0.f);
        float v4 = atomicAdd(&accf[384], 0.f);
        float v5 = atomicAdd(&accf[400], 0.f);
        float recon_low = v0 / (3.0f * (float)HW);
        float recon_eq = v1 / (float)HW;
        float denom = 2.0f * 2049.0f * 2050.0f;
        float r_smooth = (v2 + 2.f * v3) / denom;
        float ismooth = (v4 + 2.f * v5) / denom;
        out[0] = recon_low + 0.1f * ismooth + 0.1f * recon_eq + 0.01f * r_smooth;
    }
}

extern "C" void kernel_launch(void* const* d_in, const int* in_sizes, int n_in,
                              void* d_out, int out_size, void* d_ws, size_t ws_size,
                              hipStream_t stream) {
    const float* im = (const float*)d_in[0];
    const float* R = (const float*)d_in[1];
    const float* L = (const float*)d_in[2];
    float* out = (float*)d_out;
    uint32_t* ctl = (uint32_t*)d_ws;

    hipMemsetAsync(d_ws, 0, 519 * 4, stream);  // graph-capturable memset node
    hipLaunchKernelGGL(hist_k, dim3(G1H), dim3(1024), 0, stream, im, ctl);
    hipLaunchKernelGGL(main_k, dim3(G3M), dim3(1024), 0, stream, im, R, L, ctl, out);
}